// Round 2
// baseline (189.359 us; speedup 1.0000x reference)
//
#include <hip/hip_runtime.h>
#include <stdint.h>

typedef short bf16x8 __attribute__((ext_vector_type(8)));
typedef float f32x4 __attribute__((ext_vector_type(4)));

__device__ __forceinline__ unsigned short f2bf(float f) {
  uint32_t u = __float_as_uint(f);
  u = (u + 0x7FFFu + ((u >> 16) & 1u)) >> 16;
  return (unsigned short)u;
}
__device__ __forceinline__ float bf2f(unsigned short h) {
  return __uint_as_float(((uint32_t)h) << 16);
}

__device__ __forceinline__ void gload16(const void* g, void* lds) {
  const __attribute__((address_space(1))) char* gp =
      (const __attribute__((address_space(1))) char*)(uintptr_t)g;
  __attribute__((address_space(3))) char* sp =
      (__attribute__((address_space(3))) char*)(uint32_t)(uintptr_t)lds;
  __builtin_amdgcn_global_load_lds(gp, sp, 16, 0, 0);
}

// ---------------- fp32 -> bf16 convert (4 elems/thread) ----------------
__global__ void k_cvt(const float* __restrict__ src, unsigned short* __restrict__ dst, int n4) {
  int i = blockIdx.x * blockDim.x + threadIdx.x;
  if (i >= n4) return;
  float4 v = ((const float4*)src)[i];
  ushort4 o;
  o.x = f2bf(v.x); o.y = f2bf(v.y); o.z = f2bf(v.z); o.w = f2bf(v.w);
  ((ushort4*)dst)[i] = o;
}

// ---------------- bf16 GEMM: C[m][n] = sum_k A[m][k] * B[n][k] ----------------
// 128x128 tile, BK=64, 4 waves, 16x16x32 MFMA, global_load_lds staging with
// pre-swizzled source (XOR (row&7)<<4 on the 128B LDS row) for conflict-free ds_read_b128.
template <int OUTF32>
__global__ __launch_bounds__(256) void k_gemm(const unsigned short* __restrict__ A,
                                              const unsigned short* __restrict__ B,
                                              void* __restrict__ Cout,
                                              int M, int N, int K) {
  __shared__ unsigned short As[128 * 64];
  __shared__ unsigned short Bs[128 * 64];
  const int tid = threadIdx.x;
  const int w = tid >> 6, lane = tid & 63;
  const int g = lane >> 4, cl = lane & 15;
  const int nTn = N >> 7;
  const int tm = blockIdx.x / nTn, tn = blockIdx.x % nTn;
  const int m0 = tm << 7, n0 = tn << 7;
  const int wm = (w >> 1) << 6, wn = (w & 1) << 6;
  f32x4 acc[4][4] = {};
  for (int kt = 0; kt < K; kt += 64) {
    if (kt) __syncthreads();
#pragma unroll
    for (int it = 0; it < 8; ++it) {
      int cc = tid + it * 256;          // 0..2047: 2048 16B chunks (As 1024 + Bs 1024)
      int half = cc >> 10;
      int c3 = cc & 1023;
      int row = c3 >> 3, kb = (c3 & 7) << 4;
      const unsigned short* base = half ? (B + (size_t)(n0 + row) * K + kt)
                                        : (A + (size_t)(m0 + row) * K + kt);
      const char* src = (const char*)base + (kb ^ ((row & 7) << 4));
      char* dstl = (char*)(half ? Bs : As) + c3 * 16;
      gload16(src, dstl);
    }
    asm volatile("s_waitcnt vmcnt(0)" ::: "memory");
    __syncthreads();
#pragma unroll
    for (int ks = 0; ks < 2; ++ks) {
      bf16x8 af[4], bfr[4];
#pragma unroll
      for (int i = 0; i < 4; ++i) {
        int row = wm + i * 16 + cl;
        int kb = ((g << 4) + (ks << 6)) ^ ((row & 7) << 4);
        af[i] = *(const bf16x8*)((const char*)As + row * 128 + kb);
      }
#pragma unroll
      for (int j = 0; j < 4; ++j) {
        int row = wn + j * 16 + cl;
        int kb = ((g << 4) + (ks << 6)) ^ ((row & 7) << 4);
        bfr[j] = *(const bf16x8*)((const char*)Bs + row * 128 + kb);
      }
#pragma unroll
      for (int i = 0; i < 4; ++i)
#pragma unroll
        for (int j = 0; j < 4; ++j)
          acc[i][j] = __builtin_amdgcn_mfma_f32_16x16x32_bf16(af[i], bfr[j], acc[i][j], 0, 0, 0);
    }
  }
#pragma unroll
  for (int i = 0; i < 4; ++i)
#pragma unroll
    for (int j = 0; j < 4; ++j)
#pragma unroll
      for (int r = 0; r < 4; ++r) {
        int row = m0 + wm + i * 16 + (g << 2) + r;
        int col = n0 + wn + j * 16 + cl;
        float v = acc[i][j][r];
        if (OUTF32)
          ((float*)Cout)[(size_t)row * N + col] = v;
        else
          ((unsigned short*)Cout)[(size_t)row * N + col] = f2bf(v);
      }
}

// ---------------- RoPE (half-split) on Q and K, fold attn_scale*0.125 into Q ----------------
// QKV layout: [2048][3072] bf16, cols 0..2047 = Q (32 heads), 2048..2559 = K (8 heads), rest V.
__global__ void k_rope(unsigned short* __restrict__ qkv, const float* __restrict__ scale_p) {
  int idx = blockIdx.x * 256 + threadIdx.x;  // 2048 * 320 total
  int l = idx / 320;
  int u = idx - l * 320;
  int h = u >> 3;           // 0..39 (0-31 Q heads, 32-39 K heads)
  int i4 = (u & 7) << 2;    // 0,4,...,28
  int colbase = (h < 32) ? (h << 6) : (2048 + ((h - 32) << 6));
  unsigned short* p = qkv + (size_t)l * 3072 + colbase + i4;
  float sc = (h < 32) ? (scale_p[0] * 0.125f) : 1.0f;
  ushort4 a = *(const ushort4*)p;
  ushort4 b = *(const ushort4*)(p + 32);
  unsigned short av[4] = {a.x, a.y, a.z, a.w};
  unsigned short bv[4] = {b.x, b.y, b.z, b.w};
  unsigned short r1[4], r2[4];
#pragma unroll
  for (int j = 0; j < 4; ++j) {
    int i = i4 + j;
    float invf = __expf(-(float)i * 0.2878231366242557f);  // ln(10000)/32
    float ang = (float)l * invf;
    float cs = cosf(ang), sn = sinf(ang);
    float x1 = bf2f(av[j]), x2 = bf2f(bv[j]);
    r1[j] = f2bf((x1 * cs - x2 * sn) * sc);
    r2[j] = f2bf((x1 * sn + x2 * cs) * sc);
  }
  ushort4 oa = {r1[0], r1[1], r1[2], r1[3]};
  ushort4 ob = {r2[0], r2[1], r2[2], r2[3]};
  *(ushort4*)p = oa;
  *(ushort4*)(p + 32) = ob;
}

// ---------------- V transpose: VT[hk][d][l] from QKV V section ----------------
__global__ void k_vt(const unsigned short* __restrict__ qkv, unsigned short* __restrict__ vt) {
  __shared__ unsigned short tl[64][80];
  const int tid = threadIdx.x;
  const int hk = blockIdx.x >> 5, lt = blockIdx.x & 31;
  const int l0 = lt << 6;
#pragma unroll
  for (int it = 0; it < 2; ++it) {
    int cc = tid + it * 256;
    int lr = cc >> 3, d0 = (cc & 7) << 3;
    uint4 v = *(const uint4*)(qkv + (size_t)(l0 + lr) * 3072 + 2560 + hk * 64 + d0);
    *(uint4*)&tl[lr][d0] = v;
  }
  __syncthreads();
#pragma unroll
  for (int it = 0; it < 2; ++it) {
    int cc = tid + it * 256;
    int dr = cc >> 3, le = (cc & 7) << 3;
    unsigned short tmp[8] __attribute__((aligned(16)));
#pragma unroll
    for (int j = 0; j < 8; ++j) tmp[j] = tl[le + j][dr];
    *(uint4*)(vt + (size_t)(hk * 64 + dr) * 2048 + l0 + le) = *(const uint4*)tmp;
  }
}

// ---------------- Flash attention, causal, GQA ----------------
// Block = (head h, 64 q rows), 4 waves x 16 q rows. S^T = mfma(K, Q) so softmax
// stats are lane-local at q = lane&15. P round-trips through per-wave LDS.
__global__ __launch_bounds__(256) void k_attn(const unsigned short* __restrict__ qkv,
                                              const unsigned short* __restrict__ vt,
                                              unsigned short* __restrict__ ao) {
  __shared__ unsigned short Ks[64 * 64];
  __shared__ unsigned short Vs[64 * 64];  // VT chunk: [d][kv]
  __shared__ unsigned short Ps[4 * 16 * 64];
  const int tid = threadIdx.x;
  const int w = tid >> 6, lane = tid & 63;
  const int g = lane >> 4, cl = lane & 15;
  const int h = blockIdx.x >> 5;
  const int qb = blockIdx.x & 31;
  const int q0 = qb << 6;
  const int hk = h >> 2;
  const int qg = q0 + w * 16 + cl;

  const unsigned short* qptr = qkv + (size_t)qg * 3072 + h * 64 + g * 8;
  bf16x8 qf0 = *(const bf16x8*)qptr;
  bf16x8 qf1 = *(const bf16x8*)(qptr + 32);

  float m_run = -3e38f, l_run = 0.0f;
  f32x4 acc[4] = {};

  const unsigned short* kbase = qkv + 2048 + hk * 64;
  const unsigned short* vbase = vt + (size_t)hk * 64 * 2048;
  char* myP = (char*)Ps + w * 2048;

  const int nck = qb + 1;
  for (int ck = 0; ck < nck; ++ck) {
    const int kv0 = ck << 6;
    if (ck) __syncthreads();
#pragma unroll
    for (int it = 0; it < 4; ++it) {
      int cc = tid + it * 256;
      int half = cc >> 9;
      int c3 = cc & 511;
      int row = c3 >> 3, kb = (c3 & 7) << 4;
      int kbs = kb ^ ((row & 7) << 4);
      const char* src = half ? (const char*)(vbase + (size_t)row * 2048 + kv0) + kbs
                             : (const char*)(kbase + (size_t)(kv0 + row) * 3072) + kbs;
      char* dstl = (char*)(half ? Vs : Ks) + c3 * 16;
      gload16(src, dstl);
    }
    asm volatile("s_waitcnt vmcnt(0)" ::: "memory");
    __syncthreads();

    float sv[4][4];
#pragma unroll
    for (int t = 0; t < 4; ++t) {
      f32x4 st = {};
#pragma unroll
      for (int ks = 0; ks < 2; ++ks) {
        int row = t * 16 + cl;
        int kb = ((g << 4) + (ks << 6)) ^ ((row & 7) << 4);
        bf16x8 kf = *(const bf16x8*)((const char*)Ks + row * 128 + kb);
        st = __builtin_amdgcn_mfma_f32_16x16x32_bf16(kf, ks ? qf1 : qf0, st, 0, 0, 0);
      }
#pragma unroll
      for (int r = 0; r < 4; ++r) {
        int kvg = kv0 + t * 16 + (g << 2) + r;
        sv[t][r] = (kvg > qg) ? -1e9f : st[r];
      }
    }
    float pmax = -3e38f;
#pragma unroll
    for (int t = 0; t < 4; ++t)
#pragma unroll
      for (int r = 0; r < 4; ++r) pmax = fmaxf(pmax, sv[t][r]);
    pmax = fmaxf(pmax, __shfl_xor(pmax, 16));
    pmax = fmaxf(pmax, __shfl_xor(pmax, 32));
    float m_new = fmaxf(m_run, pmax);
    float fac = __expf(m_run - m_new);
    float psum = 0.0f;
    unsigned short pb[16];
#pragma unroll
    for (int t = 0; t < 4; ++t)
#pragma unroll
      for (int r = 0; r < 4; ++r) {
        float pv = __expf(sv[t][r] - m_new);
        psum += pv;
        pb[t * 4 + r] = f2bf(pv);
      }
    psum += __shfl_xor(psum, 16);
    psum += __shfl_xor(psum, 32);
    l_run = l_run * fac + psum;
    m_run = m_new;
#pragma unroll
    for (int t = 0; t < 4; ++t) {
      uint2 dd;
      dd.x = (uint32_t)pb[t * 4] | ((uint32_t)pb[t * 4 + 1] << 16);
      dd.y = (uint32_t)pb[t * 4 + 2] | ((uint32_t)pb[t * 4 + 3] << 16);
      int kb = ((t << 5) + (g << 3)) ^ ((cl & 3) << 4);
      *(uint2*)(myP + cl * 128 + kb) = dd;
    }
    float fr[4];
#pragma unroll
    for (int r = 0; r < 4; ++r) fr[r] = __shfl(fac, (g << 2) + r);
#pragma unroll
    for (int t = 0; t < 4; ++t) {
      acc[t][0] *= fr[0]; acc[t][1] *= fr[1]; acc[t][2] *= fr[2]; acc[t][3] *= fr[3];
    }
#pragma unroll
    for (int ks = 0; ks < 2; ++ks) {
      int kbp = ((g << 4) + (ks << 6)) ^ ((cl & 3) << 4);
      bf16x8 pf = *(const bf16x8*)(myP + cl * 128 + kbp);
#pragma unroll
      for (int t = 0; t < 4; ++t) {
        int row = t * 16 + cl;
        int kbv = ((g << 4) + (ks << 6)) ^ ((row & 7) << 4);
        bf16x8 vf = *(const bf16x8*)((const char*)Vs + row * 128 + kbv);
        acc[t] = __builtin_amdgcn_mfma_f32_16x16x32_bf16(pf, vf, acc[t], 0, 0, 0);
      }
    }
  }
  float li[4];
#pragma unroll
  for (int r = 0; r < 4; ++r) li[r] = 1.0f / __shfl(l_run, (g << 2) + r);
#pragma unroll
  for (int t = 0; t < 4; ++t)
#pragma unroll
    for (int r = 0; r < 4; ++r) {
      int row = q0 + w * 16 + (g << 2) + r;
      int col = h * 64 + t * 16 + cl;
      ao[(size_t)row * 2048 + col] = f2bf(acc[t][r] * li[r]);
    }
}

extern "C" void kernel_launch(void* const* d_in, const int* in_sizes, int n_in,
                              void* d_out, int out_size, void* d_ws, size_t ws_size,
                              hipStream_t stream) {
  (void)in_sizes; (void)n_in; (void)out_size; (void)ws_size;
  const float* x  = (const float*)d_in[0];
  const float* sc = (const float*)d_in[1];
  // d_in[2] = mask (causal, applied analytically)
  const float* Wq = (const float*)d_in[3];
  const float* Wk = (const float*)d_in[4];
  const float* Wv = (const float*)d_in[5];
  const float* Wo = (const float*)d_in[6];
  float* out = (float*)d_out;
  char* ws = (char*)d_ws;
  unsigned short* xb   = (unsigned short*)(ws);              // 8 MB
  unsigned short* Wcat = (unsigned short*)(ws + 8388608);    // 12 MB  [3072][2048]
  unsigned short* Wob  = (unsigned short*)(ws + 20971520);   // 8 MB
  unsigned short* QKV  = (unsigned short*)(ws + 29360128);   // 12 MB  [2048][3072]
  unsigned short* VT   = (unsigned short*)(ws + 41943040);   // 2 MB   [8][64][2048]
  unsigned short* AO   = (unsigned short*)(ws + 44040192);   // 8 MB   [2048][2048]

  k_cvt<<<4096, 256, 0, stream>>>(x, xb, 1048576);
  k_cvt<<<4096, 256, 0, stream>>>(Wq, Wcat, 1048576);
  k_cvt<<<1024, 256, 0, stream>>>(Wk, Wcat + 2048 * 2048, 262144);
  k_cvt<<<1024, 256, 0, stream>>>(Wv, Wcat + 2560 * 2048, 262144);
  k_cvt<<<4096, 256, 0, stream>>>(Wo, Wob, 1048576);
  k_gemm<0><<<384, 256, 0, stream>>>(xb, Wcat, QKV, 2048, 3072, 2048);
  k_rope<<<2560, 256, 0, stream>>>(QKV, sc);
  k_vt<<<256, 256, 0, stream>>>(QKV, VT);
  k_attn<<<1024, 256, 0, stream>>>(QKV, VT, AO);
  k_gemm<1><<<256, 256, 0, stream>>>(AO, Wob, out, 2048, 2048, 2048);
}

// Round 3
// 146.589 us; speedup vs baseline: 1.2918x; 1.2918x over previous
//
#include <hip/hip_runtime.h>
#include <stdint.h>

typedef short bf16x8 __attribute__((ext_vector_type(8)));
typedef float f32x4 __attribute__((ext_vector_type(4)));

__device__ __forceinline__ unsigned short f2bf(float f) {
  uint32_t u = __float_as_uint(f);
  u = (u + 0x7FFFu + ((u >> 16) & 1u)) >> 16;
  return (unsigned short)u;
}
__device__ __forceinline__ float bf2f(unsigned short h) {
  return __uint_as_float(((uint32_t)h) << 16);
}

__device__ __forceinline__ void gload16(const void* g, void* lds) {
  const __attribute__((address_space(1))) char* gp =
      (const __attribute__((address_space(1))) char*)(uintptr_t)g;
  __attribute__((address_space(3))) char* sp =
      (__attribute__((address_space(3))) char*)(uint32_t)(uintptr_t)lds;
  __builtin_amdgcn_global_load_lds(gp, sp, 16, 0, 0);
}

// ---------------- fused fp32 -> bf16 converts (all 5 tensors, one dispatch) ----------------
__global__ void k_cvt_all(const float* __restrict__ x, const float* __restrict__ Wq,
                          const float* __restrict__ Wk, const float* __restrict__ Wv,
                          const float* __restrict__ Wo, unsigned short* __restrict__ xb,
                          unsigned short* __restrict__ Wcat, unsigned short* __restrict__ Wob) {
  int b = blockIdx.x;
  const float* src;
  unsigned short* dst;
  int off;
  if (b < 4096)       { src = x;  dst = xb;                  off = b; }
  else if (b < 8192)  { src = Wq; dst = Wcat;                off = b - 4096; }
  else if (b < 9216)  { src = Wk; dst = Wcat + 2048 * 2048;  off = b - 8192; }
  else if (b < 10240) { src = Wv; dst = Wcat + 2560 * 2048;  off = b - 9216; }
  else                { src = Wo; dst = Wob;                  off = b - 10240; }
  int i = off * 256 + threadIdx.x;
  float4 v = ((const float4*)src)[i];
  ushort4 o;
  o.x = f2bf(v.x); o.y = f2bf(v.y); o.z = f2bf(v.z); o.w = f2bf(v.w);
  ((ushort4*)dst)[i] = o;
}

// ---------------- bf16 GEMM: C[m][n] = sum_k A[m][k] * B[n][k] ----------------
// 128x128 tile, BK=64, 4 waves, 16x16x32 MFMA, global_load_lds staging with
// pre-swizzled source (XOR (row&7)<<4 on the 128B LDS row) for conflict-free ds_read_b128.
template <int OUTF32>
__global__ __launch_bounds__(256) void k_gemm(const unsigned short* __restrict__ A,
                                              const unsigned short* __restrict__ B,
                                              void* __restrict__ Cout,
                                              int M, int N, int K) {
  __shared__ unsigned short As[128 * 64];
  __shared__ unsigned short Bs[128 * 64];
  const int tid = threadIdx.x;
  const int w = tid >> 6, lane = tid & 63;
  const int g = lane >> 4, cl = lane & 15;
  const int nTn = N >> 7;
  const int tm = blockIdx.x / nTn, tn = blockIdx.x % nTn;
  const int m0 = tm << 7, n0 = tn << 7;
  const int wm = (w >> 1) << 6, wn = (w & 1) << 6;
  f32x4 acc[4][4] = {};
  for (int kt = 0; kt < K; kt += 64) {
    if (kt) __syncthreads();
#pragma unroll
    for (int it = 0; it < 8; ++it) {
      int cc = tid + it * 256;          // 0..2047: 2048 16B chunks (As 1024 + Bs 1024)
      int half = cc >> 10;
      int c3 = cc & 1023;
      int row = c3 >> 3, kb = (c3 & 7) << 4;
      const unsigned short* base = half ? (B + (size_t)(n0 + row) * K + kt)
                                        : (A + (size_t)(m0 + row) * K + kt);
      const char* src = (const char*)base + (kb ^ ((row & 7) << 4));
      char* dstl = (char*)(half ? Bs : As) + c3 * 16;
      gload16(src, dstl);
    }
    asm volatile("s_waitcnt vmcnt(0)" ::: "memory");
    __syncthreads();
#pragma unroll
    for (int ks = 0; ks < 2; ++ks) {
      bf16x8 af[4], bfr[4];
#pragma unroll
      for (int i = 0; i < 4; ++i) {
        int row = wm + i * 16 + cl;
        int kb = ((g << 4) + (ks << 6)) ^ ((row & 7) << 4);
        af[i] = *(const bf16x8*)((const char*)As + row * 128 + kb);
      }
#pragma unroll
      for (int j = 0; j < 4; ++j) {
        int row = wn + j * 16 + cl;
        int kb = ((g << 4) + (ks << 6)) ^ ((row & 7) << 4);
        bfr[j] = *(const bf16x8*)((const char*)Bs + row * 128 + kb);
      }
#pragma unroll
      for (int i = 0; i < 4; ++i)
#pragma unroll
        for (int j = 0; j < 4; ++j)
          acc[i][j] = __builtin_amdgcn_mfma_f32_16x16x32_bf16(af[i], bfr[j], acc[i][j], 0, 0, 0);
    }
  }
#pragma unroll
  for (int i = 0; i < 4; ++i)
#pragma unroll
    for (int j = 0; j < 4; ++j)
#pragma unroll
      for (int r = 0; r < 4; ++r) {
        int row = m0 + wm + i * 16 + (g << 2) + r;
        int col = n0 + wn + j * 16 + cl;
        float v = acc[i][j][r];
        if (OUTF32)
          ((float*)Cout)[(size_t)row * N + col] = v;
        else
          ((unsigned short*)Cout)[(size_t)row * N + col] = f2bf(v);
      }
}

// ---------------- fused RoPE (Q,K in place) + V transpose ----------------
// Blocks [0,2560): RoPE. Blocks [2560,2816): V transpose into VT[hk][d][l].
__global__ void k_ropevt(unsigned short* __restrict__ qkv, const float* __restrict__ scale_p,
                         unsigned short* __restrict__ vt) {
  __shared__ unsigned short tl[64][80];
  if (blockIdx.x < 2560) {
    int idx = blockIdx.x * 256 + threadIdx.x;  // 2048 * 320 total
    int l = idx / 320;
    int u = idx - l * 320;
    int h = u >> 3;           // 0..39 (0-31 Q heads, 32-39 K heads)
    int i4 = (u & 7) << 2;    // 0,4,...,28
    int colbase = (h < 32) ? (h << 6) : (2048 + ((h - 32) << 6));
    unsigned short* p = qkv + (size_t)l * 3072 + colbase + i4;
    float sc = (h < 32) ? (scale_p[0] * 0.125f) : 1.0f;
    ushort4 a = *(const ushort4*)p;
    ushort4 b = *(const ushort4*)(p + 32);
    unsigned short av[4] = {a.x, a.y, a.z, a.w};
    unsigned short bv[4] = {b.x, b.y, b.z, b.w};
    unsigned short r1[4], r2[4];
#pragma unroll
    for (int j = 0; j < 4; ++j) {
      int i = i4 + j;
      float invf = __expf(-(float)i * 0.2878231366242557f);  // ln(10000)/32
      float ang = (float)l * invf;
      float cs = cosf(ang), sn = sinf(ang);
      float x1 = bf2f(av[j]), x2 = bf2f(bv[j]);
      r1[j] = f2bf((x1 * cs - x2 * sn) * sc);
      r2[j] = f2bf((x1 * sn + x2 * cs) * sc);
    }
    ushort4 oa = {r1[0], r1[1], r1[2], r1[3]};
    ushort4 ob = {r2[0], r2[1], r2[2], r2[3]};
    *(ushort4*)p = oa;
    *(ushort4*)(p + 32) = ob;
  } else {
    const int tid = threadIdx.x;
    const int bb = blockIdx.x - 2560;
    const int hk = bb >> 5, lt = bb & 31;
    const int l0 = lt << 6;
#pragma unroll
    for (int it = 0; it < 2; ++it) {
      int cc = tid + it * 256;
      int lr = cc >> 3, d0 = (cc & 7) << 3;
      uint4 v = *(const uint4*)(qkv + (size_t)(l0 + lr) * 3072 + 2560 + hk * 64 + d0);
      *(uint4*)&tl[lr][d0] = v;
    }
    __syncthreads();
#pragma unroll
    for (int it = 0; it < 2; ++it) {
      int cc = tid + it * 256;
      int dr = cc >> 3, le = (cc & 7) << 3;
      unsigned short tmp[8] __attribute__((aligned(16)));
#pragma unroll
      for (int j = 0; j < 8; ++j) tmp[j] = tl[le + j][dr];
      *(uint4*)(vt + (size_t)(hk * 64 + dr) * 2048 + l0 + le) = *(const uint4*)tmp;
    }
  }
}

// ---------------- Flash attention, causal, GQA, 2-phase double-buffered ----------------
// Block = (head h, 64 q rows), 4 waves x 16 q rows. S^T = mfma(K, Q) so softmax
// stats are lane-local at q = lane&15. P round-trips through per-wave LDS.
// Longest-first: qb = 31 - (blockIdx.x>>5) so 32-iteration blocks launch first.
__global__ __launch_bounds__(256) void k_attn(const unsigned short* __restrict__ qkv,
                                              const unsigned short* __restrict__ vt,
                                              unsigned short* __restrict__ ao) {
  __shared__ unsigned short Ks[2][64 * 64];
  __shared__ unsigned short Vs[2][64 * 64];  // VT chunk: [d][kv]
  __shared__ unsigned short Ps[4 * 16 * 64];
  const int tid = threadIdx.x;
  const int w = tid >> 6, lane = tid & 63;
  const int g = lane >> 4, cl = lane & 15;
  const int h = blockIdx.x & 31;
  const int qb = 31 - (blockIdx.x >> 5);
  const int q0 = qb << 6;
  const int hk = h >> 2;
  const int qg = q0 + w * 16 + cl;

  const unsigned short* qptr = qkv + (size_t)qg * 3072 + h * 64 + g * 8;
  bf16x8 qf0 = *(const bf16x8*)qptr;
  bf16x8 qf1 = *(const bf16x8*)(qptr + 32);

  float m_run = -3e38f, l_run = 0.0f;
  f32x4 acc[4] = {};

  const unsigned short* kbase = qkv + 2048 + hk * 64;
  const unsigned short* vbase = vt + (size_t)hk * 64 * 2048;
  char* myP = (char*)Ps + w * 2048;

  const int nck = qb + 1;

  auto stage = [&](int ck, int b) {
    const int kv0 = ck << 6;
#pragma unroll
    for (int it = 0; it < 4; ++it) {
      int cc = tid + it * 256;
      int half = cc >> 9;
      int c3 = cc & 511;
      int row = c3 >> 3, kb = (c3 & 7) << 4;
      int kbs = kb ^ ((row & 7) << 4);
      const char* src = half ? (const char*)(vbase + (size_t)row * 2048 + kv0) + kbs
                             : (const char*)(kbase + (size_t)(kv0 + row) * 3072) + kbs;
      char* dstl = (char*)(half ? Vs[b] : Ks[b]) + c3 * 16;
      gload16(src, dstl);
    }
  };

  stage(0, 0);
  asm volatile("s_waitcnt vmcnt(0)" ::: "memory");
  __syncthreads();
  int cur = 0;

  for (int ck = 0; ck < nck; ++ck) {
    if (ck + 1 < nck) stage(ck + 1, cur ^ 1);  // prefetch next tile into other buffer
    const int kv0 = ck << 6;
    const char* Kc = (const char*)Ks[cur];
    const char* Vc = (const char*)Vs[cur];

    float sv[4][4];
#pragma unroll
    for (int t = 0; t < 4; ++t) {
      f32x4 st = {};
#pragma unroll
      for (int ks = 0; ks < 2; ++ks) {
        int row = t * 16 + cl;
        int kb = ((g << 4) + (ks << 6)) ^ ((row & 7) << 4);
        bf16x8 kf = *(const bf16x8*)(Kc + row * 128 + kb);
        st = __builtin_amdgcn_mfma_f32_16x16x32_bf16(kf, ks ? qf1 : qf0, st, 0, 0, 0);
      }
#pragma unroll
      for (int r = 0; r < 4; ++r) {
        int kvg = kv0 + t * 16 + (g << 2) + r;
        sv[t][r] = (kvg > qg) ? -1e9f : st[r];
      }
    }
    float pmax = -3e38f;
#pragma unroll
    for (int t = 0; t < 4; ++t)
#pragma unroll
      for (int r = 0; r < 4; ++r) pmax = fmaxf(pmax, sv[t][r]);
    pmax = fmaxf(pmax, __shfl_xor(pmax, 16));
    pmax = fmaxf(pmax, __shfl_xor(pmax, 32));
    float m_new = fmaxf(m_run, pmax);
    float fac = __expf(m_run - m_new);
    float psum = 0.0f;
    unsigned short pb[16];
#pragma unroll
    for (int t = 0; t < 4; ++t)
#pragma unroll
      for (int r = 0; r < 4; ++r) {
        float pv = __expf(sv[t][r] - m_new);
        psum += pv;
        pb[t * 4 + r] = f2bf(pv);
      }
    psum += __shfl_xor(psum, 16);
    psum += __shfl_xor(psum, 32);
    l_run = l_run * fac + psum;
    m_run = m_new;
#pragma unroll
    for (int t = 0; t < 4; ++t) {
      uint2 dd;
      dd.x = (uint32_t)pb[t * 4] | ((uint32_t)pb[t * 4 + 1] << 16);
      dd.y = (uint32_t)pb[t * 4 + 2] | ((uint32_t)pb[t * 4 + 3] << 16);
      int kb = ((t << 5) + (g << 3)) ^ ((cl & 3) << 4);
      *(uint2*)(myP + cl * 128 + kb) = dd;
    }
    float fr[4];
#pragma unroll
    for (int r = 0; r < 4; ++r) fr[r] = __shfl(fac, (g << 2) + r);
#pragma unroll
    for (int t = 0; t < 4; ++t) {
      acc[t][0] *= fr[0]; acc[t][1] *= fr[1]; acc[t][2] *= fr[2]; acc[t][3] *= fr[3];
    }
#pragma unroll
    for (int ks = 0; ks < 2; ++ks) {
      int kbp = ((g << 4) + (ks << 6)) ^ ((cl & 3) << 4);
      bf16x8 pf = *(const bf16x8*)(myP + cl * 128 + kbp);
#pragma unroll
      for (int t = 0; t < 4; ++t) {
        int row = t * 16 + cl;
        int kbv = ((g << 4) + (ks << 6)) ^ ((row & 7) << 4);
        bf16x8 vf = *(const bf16x8*)(Vc + row * 128 + kbv);
        acc[t] = __builtin_amdgcn_mfma_f32_16x16x32_bf16(pf, vf, acc[t], 0, 0, 0);
      }
    }
    asm volatile("s_waitcnt vmcnt(0)" ::: "memory");  // next tile fully staged
    __syncthreads();                                   // all waves done reading cur
    cur ^= 1;
  }
  float li[4];
#pragma unroll
  for (int r = 0; r < 4; ++r) li[r] = 1.0f / __shfl(l_run, (g << 2) + r);
#pragma unroll
  for (int t = 0; t < 4; ++t)
#pragma unroll
    for (int r = 0; r < 4; ++r) {
      int row = q0 + w * 16 + (g << 2) + r;
      int col = h * 64 + t * 16 + cl;
      ao[(size_t)row * 2048 + col] = f2bf(acc[t][r] * li[r]);
    }
}

extern "C" void kernel_launch(void* const* d_in, const int* in_sizes, int n_in,
                              void* d_out, int out_size, void* d_ws, size_t ws_size,
                              hipStream_t stream) {
  (void)in_sizes; (void)n_in; (void)out_size; (void)ws_size;
  const float* x  = (const float*)d_in[0];
  const float* sc = (const float*)d_in[1];
  // d_in[2] = mask (causal, applied analytically)
  const float* Wq = (const float*)d_in[3];
  const float* Wk = (const float*)d_in[4];
  const float* Wv = (const float*)d_in[5];
  const float* Wo = (const float*)d_in[6];
  float* out = (float*)d_out;
  char* ws = (char*)d_ws;
  unsigned short* xb   = (unsigned short*)(ws);              // 8 MB
  unsigned short* Wcat = (unsigned short*)(ws + 8388608);    // 12 MB  [3072][2048]
  unsigned short* Wob  = (unsigned short*)(ws + 20971520);   // 8 MB
  unsigned short* QKV  = (unsigned short*)(ws + 29360128);   // 12 MB  [2048][3072]
  unsigned short* VT   = (unsigned short*)(ws + 41943040);   // 2 MB   [8][64][2048]
  unsigned short* AO   = (unsigned short*)(ws + 44040192);   // 8 MB   [2048][2048]

  k_cvt_all<<<14336, 256, 0, stream>>>(x, Wq, Wk, Wv, Wo, xb, Wcat, Wob);
  k_gemm<0><<<384, 256, 0, stream>>>(xb, Wcat, QKV, 2048, 3072, 2048);
  k_ropevt<<<2816, 256, 0, stream>>>(QKV, sc, VT);
  k_attn<<<1024, 256, 0, stream>>>(QKV, VT, AO);
  k_gemm<1><<<256, 256, 0, stream>>>(AO, Wob, out, 2048, 2048, 2048);
}